// Round 1
// 647.143 us; speedup vs baseline: 1.0460x; 1.0460x over previous
//
#include <hip/hip_runtime.h>
#include <math.h>

// Problem constants (fixed by setup_inputs): B=256, K=512, D=1024, T=0.07
#define B_N 256
#define K_N 512
#define D_N 1024
#define INV_T 14.285714285714286   // 1/0.07 in double

typedef float vf4 __attribute__((ext_vector_type(4)));

// ws layout (no initialization required — every slot is written):
//   [0,     65536): double block_part[8192]  (one per block, plain store)
//   [65536, 67584): double fg_part[256]      (one per b, written by the fg-wave)

// Single fused streaming kernel.
// 8192 blocks x 256 threads = 32768 waves; each wave owns 4 consecutive
// (b,k) rows (4 KiB each, same b since 512 % 4 == 0). The wave:
//   - loads its bg_img row (4 KiB, L2-resident, reused 128x across waves)
//   - issues all 16 nontemporal row loads up front (16 KiB in flight)
//   - computes |a|^2 AND the 4 dots with 4-way ILP vf4 FMA trees
//   - runs 5 butterfly chains interleaved (ss, s0..s3) -> results on ALL lanes
//   - computes inv_norm itself (no producer kernel, no dependency)
//   - all-lane expf (no exec-mask churn), double accumulate
//   - one wave per b additionally handles the fg row
__global__ __launch_bounds__(256) void dot_exp_fused(
    const float* __restrict__ bg_img, const float* __restrict__ fg_pro,
    const float* __restrict__ bg_pro,
    double* __restrict__ block_part, double* __restrict__ fg_part)
{
  const int lane  = threadIdx.x & 63;
  const int wib   = threadIdx.x >> 6;                // wave in block (0..3)
  const int gwave = blockIdx.x * 4 + wib;            // 0..32767
  const int r0    = gwave * 4;                       // first of 4 (b,k) rows
  const int b     = r0 >> 9;                         // K = 512

  // bg_img row fragment: lane i holds elements [4i, 4i+3] of 4 blocks of 256
  const vf4* a4 = (const vf4*)(bg_img + (size_t)b * D_N);
  const vf4 a0 = a4[lane];
  const vf4 a1 = a4[lane + 64];
  const vf4 a2 = a4[lane + 128];
  const vf4 a3 = a4[lane + 192];

  // Issue ALL 16 streaming loads before any reduction work.
  const vf4* p4 = (const vf4*)(bg_pro + (size_t)r0 * D_N);
  vf4 x0[4], x1[4], x2[4], x3[4];
  #pragma unroll
  for (int j = 0; j < 4; ++j) {
    const vf4* r = p4 + j * 256;                     // 256 vf4 per row
    x0[j] = __builtin_nontemporal_load(r + lane);
    x1[j] = __builtin_nontemporal_load(r + lane + 64);
    x2[j] = __builtin_nontemporal_load(r + lane + 128);
    x3[j] = __builtin_nontemporal_load(r + lane + 192);
  }

  // |a|^2 partial (for in-wave norm) — 4-way ILP
  float ss;
  {
    vf4 m = a0 * a0 + a1 * a1 + a2 * a2 + a3 * a3;
    ss = (m.x + m.y) + (m.z + m.w);
  }

  // 4 row-dot partials — independent 4-way ILP FMA trees
  float s[4];
  #pragma unroll
  for (int j = 0; j < 4; ++j) {
    vf4 m = a0 * x0[j] + a1 * x1[j] + a2 * x2[j] + a3 * x3[j];
    s[j] = (m.x + m.y) + (m.z + m.w);
  }

  // 5 interleaved butterfly chains; results broadcast to all 64 lanes.
  #pragma unroll
  for (int off = 32; off > 0; off >>= 1) {
    ss   += __shfl_xor(ss,   off);
    s[0] += __shfl_xor(s[0], off);
    s[1] += __shfl_xor(s[1], off);
    s[2] += __shfl_xor(s[2], off);
    s[3] += __shfl_xor(s[3], off);
  }

  const double inv   = 1.0 / sqrt((double)ss);       // one DP op per wave
  const float  scale = (float)(inv * INV_T);

  // All lanes compute the same thing — no divergence, no serial lane-0 section.
  const double e = (double)expf(s[0] * scale) + (double)expf(s[1] * scale)
                 + (double)expf(s[2] * scale) + (double)expf(s[3] * scale);

  // fg logit: exactly one wave per b (r0 multiple of 512), wave-uniform branch.
  if ((r0 & (K_N - 1)) == 0) {
    const vf4* f4 = (const vf4*)(fg_pro + (size_t)b * D_N);
    vf4 m = a0 * f4[lane] + a1 * f4[lane + 64]
          + a2 * f4[lane + 128] + a3 * f4[lane + 192];
    float fs = (m.x + m.y) + (m.z + m.w);
    #pragma unroll
    for (int off = 32; off > 0; off >>= 1) fs += __shfl_xor(fs, off);
    if (lane == 0) fg_part[b] = exp((double)fs * inv * INV_T);
  }

  // Block combine: plain store, no atomics, no init required.
  __shared__ double wacc[4];
  if (lane == 0) wacc[wib] = e;
  __syncthreads();
  if (threadIdx.x == 0)
    block_part[blockIdx.x] = (wacc[0] + wacc[1]) + (wacc[2] + wacc[3]);
}

// Final scalar: reduce 8192 block partials (64 KiB, coalesced) + 256 fg parts.
__global__ __launch_bounds__(256) void finalize_kernel(
    const double* __restrict__ block_part, const double* __restrict__ fg_part,
    float* __restrict__ out)
{
  const int t = threadIdx.x;
  double v = 0.0;
  #pragma unroll
  for (int i = 0; i < 32; ++i) v += block_part[t + 256 * i];
  double f = fg_part[t];
  #pragma unroll
  for (int off = 32; off > 0; off >>= 1) {
    v += __shfl_xor(v, off);
    f += __shfl_xor(f, off);
  }
  __shared__ double wv[4], wf[4];
  const int w = t >> 6;
  if ((t & 63) == 0) { wv[w] = v; wf[w] = f; }
  __syncthreads();
  if (t == 0) {
    double pos = ((wv[0] + wv[1]) + (wv[2] + wv[3])) / (double)K_N; // sum_b mean_k
    double fg  = (wf[0] + wf[1]) + (wf[2] + wf[3]);
    out[0] = (float)log1p(fg / pos);   // -log(pos/neg) = log1p(fgsum/pos)
  }
}

extern "C" void kernel_launch(void* const* d_in, const int* in_sizes, int n_in,
                              void* d_out, int out_size, void* d_ws, size_t ws_size,
                              hipStream_t stream) {
  const float* bg_img = (const float*)d_in[0];   // (B, D)
  const float* fg_pro = (const float*)d_in[1];   // (B, D)
  const float* bg_pro = (const float*)d_in[2];   // (B, K, D)

  char* ws = (char*)d_ws;
  double* block_part = (double*)(ws);            // 8192 doubles
  double* fg_part    = (double*)(ws + 65536);    // 256 doubles

  // 131072 (b,k) rows / (4 waves/block * 4 rows/wave) = 8192 blocks.
  // No memset, no producer kernel: 2 dispatches total.
  dot_exp_fused<<<(B_N * K_N) / 16, 256, 0, stream>>>(
      bg_img, fg_pro, bg_pro, block_part, fg_part);
  finalize_kernel<<<1, 256, 0, stream>>>(block_part, fg_part, (float*)d_out);
}